// Round 5
// baseline (589.264 us; speedup 1.0000x reference)
//
#include <hip/hip_runtime.h>
#include <hip/hip_bf16.h>
#include <math.h>

#define NN 8192
#define DD 512
#define INV_T 14.285714285714286f   // 1/0.07 ; also the logits_max (diagonal) value

typedef __attribute__((ext_vector_type(8))) short s16x8;  // 8 bf16 = 4 VGPRs
typedef __attribute__((ext_vector_type(4))) float f32x4;

__device__ __forceinline__ unsigned short f32_to_bf16(float f) {
  unsigned int u = __float_as_uint(f);
  u += 0x7FFFu + ((u >> 16) & 1u);   // round-to-nearest-even
  return (unsigned short)(u >> 16);
}

__device__ __forceinline__ void async16(const void* g, void* l) {
  // 16B-wide global->LDS DMA; LDS dest must be wave-uniform base + lane*16
  __builtin_amdgcn_global_load_lds((__attribute__((address_space(1))) void*)(void*)g,
                                   (__attribute__((address_space(3))) void*)l,
                                   16, 0, 0);
}

// ballot-pack one 16-load batch into the pk bit array
__device__ __forceinline__ void consume_masks(const int* mv, int kdp, int t0,
                                              unsigned long long (*pk)[128][2],
                                              int lane) {
  #pragma unroll
  for (int j = 0; j < 16; ++j) {
    const unsigned long long b = __ballot(mv[j] != 0);
    if (lane == j) pk[kdp][t0 + (j >> 1)][j & 1] = b;
  }
}

// ---------------- Kernel A: normalize rows, emit bf16 (+ zero accumulators) ----
__global__ __launch_bounds__(256) void normalize_kernel(const float* __restrict__ f,
                                                        unsigned short* __restrict__ fnb,
                                                        float* __restrict__ acc) {
  // fold the 96KB accumulator memset into this kernel: 96 blocks x 256 floats
  if (blockIdx.x < 96) acc[blockIdx.x * 256 + threadIdx.x] = 0.f;

  const int wave = threadIdx.x >> 6;
  const int lane = threadIdx.x & 63;
  const int row  = blockIdx.x * 4 + wave;
  const float* src = f + (size_t)row * DD + lane * 8;
  float4 v0 = *(const float4*)src;
  float4 v1 = *(const float4*)(src + 4);
  float ss = v0.x*v0.x + v0.y*v0.y + v0.z*v0.z + v0.w*v0.w
           + v1.x*v1.x + v1.y*v1.y + v1.z*v1.z + v1.w*v1.w;
  #pragma unroll
  for (int o = 32; o; o >>= 1) ss += __shfl_xor(ss, o);
  const float r = 1.0f / fmaxf(sqrtf(ss), 1e-8f);
  ushort4 a, b;
  a.x = f32_to_bf16(v0.x * r); a.y = f32_to_bf16(v0.y * r);
  a.z = f32_to_bf16(v0.z * r); a.w = f32_to_bf16(v0.w * r);
  b.x = f32_to_bf16(v1.x * r); b.y = f32_to_bf16(v1.y * r);
  b.z = f32_to_bf16(v1.z * r); b.w = f32_to_bf16(v1.w * r);
  unsigned short* dst = fnb + (size_t)row * DD + lane * 8;
  *(ushort4*)dst = a;
  *(ushort4*)(dst + 4) = b;
}

// ---------------- Kernel B: single fused kernel ----------------
// 128x128 tile per block, 4 waves each 64x64 (4x4 of 16x16x32 bf16 MFMA).
// R5: R4's ballot bit-pack structure (proven correct) with a counted-vmcnt
// schedule (T3/T4). Mask loads issued at iter kk are consumed at the TOP of
// iter kk+1 — a full iteration (~2000cy) of latency cover. Barriers are RAW
// s_barrier: the mid-barrier uses s_waitcnt vmcnt(16) so the 2 staging loads
// (oldest in the FIFO) are drained while the 16 mask loads stay in flight
// across the barrier + MFMA phase. sched_barrier(0) fences pin vmem issue
// order (staging MUST be oldest or vmcnt(16) is unsound). R2/R4 lesson:
// __syncthreads' vmcnt(0) drain is what kept poisoning in-loop mask traffic.
// Epilogue: zero global loads (bits from LDS).
__global__ __launch_bounds__(256, 3) void fused_kernel(const unsigned short* __restrict__ fnb,
                                                       const int* __restrict__ posm,
                                                       const int* __restrict__ negm,
                                                       float* __restrict__ Spos,
                                                       float* __restrict__ Sneg,
                                                       float* __restrict__ Pcnt) {
  // decode compact triangular block id -> (bi, bj), bi <= bj, 64x64 block grid
  const int bid = blockIdx.x;
  int bi = (int)(64.5 - sqrt(64.5 * 64.5 - 2.0 * (double)bid));
  while (64 * bi - bi * (bi - 1) / 2 > bid) --bi;
  while (64 * (bi + 1) - (bi + 1) * bi / 2 <= bid) ++bi;
  const int bj = bi + (bid - (64 * bi - bi * (bi - 1) / 2));
  const int I = bi * 128;
  const int J = bj * 128;
  const bool offdiag = (bi != bj);

  const int tid  = threadIdx.x;
  const int wave = tid >> 6;
  const int lane = tid & 63;
  const int wm = wave >> 1;            // 0..1 row half
  const int wn = wave & 1;             // 0..1 col half
  const int q   = lane >> 4;           // 0..3
  const int c16 = lane & 15;           // 0..15

  __shared__ alignas(16) unsigned short lA[128 * 32];
  __shared__ alignas(16) unsigned short lB[128 * 32];
  __shared__ float sacc[2][128][3];    // [panel][row][Spos,Sneg,Pcnt]
  // packed mask bits: [kind][row][word64]; kind 0=posD 1=negD 2=posT 3=negT
  __shared__ unsigned long long pk[4][128][2];
  for (int t = tid; t < 2 * 128 * 3; t += 256) ((float*)sacc)[t] = 0.f;

  // ---- GEMM + pipelined mask bit-pack stream ----
  f32x4 acc[4][4];
  const f32x4 z4 = {0.f, 0.f, 0.f, 0.f};
  #pragma unroll
  for (int mt = 0; mt < 4; ++mt)
    #pragma unroll
    for (int nt = 0; nt < 4; ++nt) acc[mt][nt] = z4;

  int mv[16];   // in-flight mask batch (lives across the mid/end barriers)

  for (int kk = 0; kk < DD / 32; ++kk) {
    const int k0    = kk * 32;
    const int kd    = kk & 3;
    const int slice = kk >> 2;
    const bool mact = (kd < 2) || offdiag;          // block-uniform

    // consume PREVIOUS iteration's mask loads (full iteration of cover);
    // compiler emits progressive counted vmcnt waits for the mv registers.
    if (kk > 0 && ((((kk - 1) & 3) < 2) || offdiag)) {
      consume_masks(mv, (kk - 1) & 3, ((kk - 1) >> 2) * 32 + wave * 8, pk, lane);
    }

    // staging: must be the OLDEST vmem ops this iteration
    #pragma unroll
    for (int c = 0; c < 2; ++c) {
      const int fidx = tid + c * 256;        // 0..511 16B-chunks
      const int L    = fidx >> 2;            // LDS row 0..127
      const int p    = fidx & 3;
      const int csrc = (p ^ ((L >> 1) & 3)) & 3;     // chunk XOR swizzle
      // lA: natural row order (R8-proven, 0 conflicts)
      async16(fnb + (size_t)(I + L) * DD + k0 + csrc * 8, (char*)lA + fidx * 16);
      // lB: row-permuted so MFMA B-reads (global row 4*c16+t) stay 2-way in banks
      const int gB = 4 * (L & 31) + (L >> 5);        // inverse of L(brow)
      async16(fnb + (size_t)(J + gB) * DD + k0 + csrc * 8, (char*)lB + fidx * 16);
    }
    __builtin_amdgcn_sched_barrier(0);   // staging stays before mask loads

    // mask loads for THIS iteration: stay in flight across barrier + MFMA
    if (mact) {
      const int rbase = (kd & 2) ? J : I;
      const int cbase = (kd & 2) ? I : J;
      const int* __restrict__ mp = (kd & 1) ? negm : posm;
      const int trow0 = slice * 32 + wave * 8;
      #pragma unroll
      for (int j = 0; j < 16; ++j) {
        const int trow = trow0 + (j >> 1);
        mv[j] = mp[(size_t)(rbase + trow) * NN + cbase + (j & 1) * 64 + lane];
      }
    }
    __builtin_amdgcn_sched_barrier(0);

    // mid barrier: drain staging ONLY (2 oldest); keep 16 mask loads in flight
    if (mact) asm volatile("s_waitcnt vmcnt(16)" ::: "memory");
    else      asm volatile("s_waitcnt vmcnt(0)"  ::: "memory");
    __builtin_amdgcn_sched_barrier(0);
    __builtin_amdgcn_s_barrier();
    __builtin_amdgcn_sched_barrier(0);

    s16x8 aF[4], bF[4];
    #pragma unroll
    for (int t = 0; t < 4; ++t) {
      const int arow = wm * 64 + t * 16 + c16;
      const int apos = (q ^ ((arow >> 1) & 3)) & 3;
      aF[t] = *(const s16x8*)((const char*)lA + arow * 64 + apos * 16);
      // want global row brow = wn*64 + 4*c16 + t  ->  LDS row L(brow)
      const int Lb = (wn * 16 + c16) | (t << 5);
      const int bpos = (q ^ ((Lb >> 1) & 3)) & 3;
      bF[t] = *(const s16x8*)((const char*)lB + Lb * 64 + bpos * 16);
    }
    #pragma unroll
    for (int mt = 0; mt < 4; ++mt)
      #pragma unroll
      for (int nt = 0; nt < 4; ++nt)
        acc[mt][nt] = __builtin_amdgcn_mfma_f32_16x16x32_bf16(aF[mt], bF[nt], acc[mt][nt], 0, 0, 0);

    // end barrier: protect lA/lB for next staging; NO vmem drain (masks fly on)
    __builtin_amdgcn_sched_barrier(0);
    __builtin_amdgcn_s_barrier();
    __builtin_amdgcn_sched_barrier(0);
  }

  // final mask batch (kk=15 is kind 3 -> only off-diagonal blocks issued it)
  if (offdiag) consume_masks(mv, 3, 3 * 32 + wave * 8, pk, lane);
  __syncthreads();   // full drain + barrier: pk complete & visible to all

  // ---- epilogue: pure LDS/VALU, no global loads ----
  // acc[mt][nt][r] = sim[I + wm*64 + mt*16 + q*4 + r][J + wn*64 + 4*c16 + nt]
  #pragma unroll
  for (int mt = 0; mt < 4; ++mt)
    #pragma unroll
    for (int nt = 0; nt < 4; ++nt)
      #pragma unroll
      for (int r = 0; r < 4; ++r)
        acc[mt][nt][r] = __expf(acc[mt][nt][r] * INV_T - INV_T);

  const bool hasdiag = (bi == bj) && (wm == wn);
  const int cb = wn * 64 + 4 * c16;            // local col base
  const int half = c16 >> 3;                   // which 32b half of the 64b word
  const int bsh  = 4 * (c16 & 7);              // bit base within the half

  // direct pass: rows I.., cols J..
  #pragma unroll
  for (int mt = 0; mt < 4; ++mt) {
    const int rl = wm * 64 + mt * 16 + q * 4;  // local row base
    #pragma unroll
    for (int r = 0; r < 4; ++r) {
      const int row = rl + r;
      const uint2 pw = *(const uint2*)&pk[0][row][wn];
      const uint2 nw = *(const uint2*)&pk[1][row][wn];
      const unsigned int p32 = half ? pw.y : pw.x;
      const unsigned int n32 = half ? nw.y : nw.x;
      float dsp = 0.f, dsn = 0.f, dpc = 0.f;
      #pragma unroll
      for (int nt = 0; nt < 4; ++nt) {
        float pf = (float)((p32 >> (bsh + nt)) & 1u);
        float nf = (float)((n32 >> (bsh + nt)) & 1u);
        if (hasdiag && (row == cb + nt)) { pf = 0.f; nf = 0.f; }  // self-contrast diag
        const float e = acc[mt][nt][r];
        dsp = fmaf(e, pf, dsp);
        dsn = fmaf(e, nf, dsn);
        dpc += pf;
      }
      #pragma unroll
      for (int o = 1; o <= 8; o <<= 1) {
        dsp += __shfl_xor(dsp, o);
        dsn += __shfl_xor(dsn, o);
        dpc += __shfl_xor(dpc, o);
      }
      if (c16 == 0) {   // LDS atomics: lgkmcnt only
        atomicAdd(&sacc[0][row][0], dsp);
        atomicAdd(&sacc[0][row][1], dsn);
        atomicAdd(&sacc[0][row][2], dpc);
      }
    }
  }

  // transposed pass: sim(col,row) == sim(row,col); rows J.., cols I..
  if (offdiag) {
    #pragma unroll
    for (int nt = 0; nt < 4; ++nt) {
      const int trl = cb + nt;                 // local row in J-panel
      const uint2 pw = *(const uint2*)&pk[2][trl][wm];
      const uint2 nw = *(const uint2*)&pk[3][trl][wm];
      float ts = 0.f, tn = 0.f, tp = 0.f;
      #pragma unroll
      for (int mt = 0; mt < 4; ++mt) {
        const unsigned int p32 = (mt < 2) ? pw.x : pw.y;
        const unsigned int n32 = (mt < 2) ? nw.x : nw.y;
        #pragma unroll
        for (int r = 0; r < 4; ++r) {
          const int bit = (mt & 1) * 16 + q * 4 + r;
          const float pf = (float)((p32 >> bit) & 1u);
          const float nf = (float)((n32 >> bit) & 1u);
          const float e = acc[mt][nt][r];
          ts = fmaf(e, pf, ts);
          tn = fmaf(e, nf, tn);
          tp += pf;
        }
      }
      ts += __shfl_xor(ts, 16); ts += __shfl_xor(ts, 32);
      tn += __shfl_xor(tn, 16); tn += __shfl_xor(tn, 32);
      tp += __shfl_xor(tp, 16); tp += __shfl_xor(tp, 32);
      if (q == 0) {
        atomicAdd(&sacc[1][trl][0], ts);
        atomicAdd(&sacc[1][trl][1], tn);
        atomicAdd(&sacc[1][trl][2], tp);
      }
    }
  }

  __syncthreads();

  // one batch of global atomics at the very end; nothing waits on them
  const int r = tid & 127;
  if (tid < 128) {
    atomicAdd(&Spos[I + r], sacc[0][r][0]);
    atomicAdd(&Sneg[I + r], sacc[0][r][1]);
    atomicAdd(&Pcnt[I + r], sacc[0][r][2]);
  } else if (offdiag) {
    atomicAdd(&Spos[J + r], sacc[1][r][0]);
    atomicAdd(&Sneg[J + r], sacc[1][r][1]);
    atomicAdd(&Pcnt[J + r], sacc[1][r][2]);
  }
}

// ---------------- Kernel C: finalize ----------------
__global__ __launch_bounds__(256) void finalize_kernel(const float* __restrict__ Spos,
                                                       const float* __restrict__ Sneg,
                                                       const float* __restrict__ Pcnt,
                                                       float* __restrict__ out) {
  float local = 0.f;
  for (int i = threadIdx.x; i < NN; i += 256) {
    const float sp = Spos[i], sn = Sneg[i], pc = Pcnt[i];
    const float card = (pc == 0.f) ? 1.f : pc;
    local += (logf(sn) * pc - sp) / card;
  }
  #pragma unroll
  for (int o = 32; o; o >>= 1) local += __shfl_xor(local, o);
  __shared__ float red[4];
  if ((threadIdx.x & 63) == 0) red[threadIdx.x >> 6] = local;
  __syncthreads();
  if (threadIdx.x == 0)
    out[0] = (red[0] + red[1] + red[2] + red[3]) * (1.0f / (float)NN);
}

extern "C" void kernel_launch(void* const* d_in, const int* in_sizes, int n_in,
                              void* d_out, int out_size, void* d_ws, size_t ws_size,
                              hipStream_t stream) {
  const float* feat = (const float*)d_in[0];
  const int* posm   = (const int*)d_in[1];
  const int* negm   = (const int*)d_in[2];
  float* out = (float*)d_out;

  char* ws = (char*)d_ws;
  unsigned short* fnb = (unsigned short*)ws;                 // 8 MB
  float* Spos = (float*)(ws + (size_t)8 * 1024 * 1024);
  float* Sneg = Spos + NN;
  float* Pcnt = Sneg + NN;

  normalize_kernel<<<NN / 4, 256, 0, stream>>>(feat, fnb, Spos);
  fused_kernel<<<2080, 256, 0, stream>>>(fnb, posm, negm, Spos, Sneg, Pcnt);
  finalize_kernel<<<1, 256, 0, stream>>>(Spos, Sneg, Pcnt, out);
}

// Round 6
// 583.589 us; speedup vs baseline: 1.0097x; 1.0097x over previous
//
#include <hip/hip_runtime.h>
#include <hip/hip_bf16.h>
#include <math.h>

#define NN 8192
#define DD 512
#define INV_T 14.285714285714286f   // 1/0.07 ; also the logits_max (diagonal) value

typedef __attribute__((ext_vector_type(8))) short s16x8;  // 8 bf16 = 4 VGPRs
typedef __attribute__((ext_vector_type(4))) float f32x4;

__device__ __forceinline__ unsigned short f32_to_bf16(float f) {
  unsigned int u = __float_as_uint(f);
  u += 0x7FFFu + ((u >> 16) & 1u);   // round-to-nearest-even
  return (unsigned short)(u >> 16);
}

__device__ __forceinline__ void async16(const void* g, void* l) {
  // 16B-wide global->LDS DMA; LDS dest must be wave-uniform base + lane*16
  __builtin_amdgcn_global_load_lds((__attribute__((address_space(1))) void*)(void*)g,
                                   (__attribute__((address_space(3))) void*)l,
                                   16, 0, 0);
}

// ballot-pack one 16-load batch into the pk bit array (row stride 3 = pad)
__device__ __forceinline__ void consume_masks(const int* mv, int kdp, int t0,
                                              unsigned long long (*pk)[128][3],
                                              int lane) {
  #pragma unroll
  for (int j = 0; j < 16; ++j) {
    const unsigned long long b = __ballot(mv[j] != 0);
    if (lane == j) pk[kdp][t0 + (j >> 1)][j & 1] = b;
  }
}

// ---------------- Kernel A: normalize rows, emit bf16 (+ zero accumulators) ----
__global__ __launch_bounds__(256) void normalize_kernel(const float* __restrict__ f,
                                                        unsigned short* __restrict__ fnb,
                                                        float* __restrict__ acc) {
  // fold the 96KB accumulator memset into this kernel: 96 blocks x 256 floats
  if (blockIdx.x < 96) acc[blockIdx.x * 256 + threadIdx.x] = 0.f;

  const int wave = threadIdx.x >> 6;
  const int lane = threadIdx.x & 63;
  const int row  = blockIdx.x * 4 + wave;
  const float* src = f + (size_t)row * DD + lane * 8;
  float4 v0 = *(const float4*)src;
  float4 v1 = *(const float4*)(src + 4);
  float ss = v0.x*v0.x + v0.y*v0.y + v0.z*v0.z + v0.w*v0.w
           + v1.x*v1.x + v1.y*v1.y + v1.z*v1.z + v1.w*v1.w;
  #pragma unroll
  for (int o = 32; o; o >>= 1) ss += __shfl_xor(ss, o);
  const float r = 1.0f / fmaxf(sqrtf(ss), 1e-8f);
  ushort4 a, b;
  a.x = f32_to_bf16(v0.x * r); a.y = f32_to_bf16(v0.y * r);
  a.z = f32_to_bf16(v0.z * r); a.w = f32_to_bf16(v0.w * r);
  b.x = f32_to_bf16(v1.x * r); b.y = f32_to_bf16(v1.y * r);
  b.z = f32_to_bf16(v1.z * r); b.w = f32_to_bf16(v1.w * r);
  unsigned short* dst = fnb + (size_t)row * DD + lane * 8;
  *(ushort4*)dst = a;
  *(ushort4*)(dst + 4) = b;
}

// ---------------- Kernel B: single fused kernel, wave-specialized ----------------
// 512 threads: waves 0-3 = GEMM (128x128 tile, 4x4 of 16x16x32 bf16 MFMA,
// m97-style staged loop with __syncthreads), waves 4-7 = MASK LOADERS.
// R2/R4/R5 lesson: mask traffic in the COMPUTE waves' vmem queue always
// loses (barrier vmcnt(0) drain, or queue/issue coupling even with counted
// waits). Producer-consumer wave specialization decouples them:
//  - loader wave w streams 8 rows x 128 cols of one mask kind per iter
//    (16 coalesced dword loads), arrives at two RAW s_barriers WITHOUT
//    draining, and ballot-packs the batch one full iteration later.
//  - GEMM waves keep plain __syncthreads (drains only their own staging).
//  - barrier counts match exactly (2 per iter in both roles).
// Epilogue: zero global loads — bits from pk LDS (R4-proven layout).
// pk row-padded to 3 words to cut transposed-pass bank conflicts 8->4 way.
__global__ __launch_bounds__(512, 4) void fused_kernel(const unsigned short* __restrict__ fnb,
                                                       const int* __restrict__ posm,
                                                       const int* __restrict__ negm,
                                                       float* __restrict__ Spos,
                                                       float* __restrict__ Sneg,
                                                       float* __restrict__ Pcnt) {
  // decode compact triangular block id -> (bi, bj), bi <= bj, 64x64 block grid
  const int bid = blockIdx.x;
  int bi = (int)(64.5 - sqrt(64.5 * 64.5 - 2.0 * (double)bid));
  while (64 * bi - bi * (bi - 1) / 2 > bid) --bi;
  while (64 * (bi + 1) - (bi + 1) * bi / 2 <= bid) ++bi;
  const int bj = bi + (bid - (64 * bi - bi * (bi - 1) / 2));
  const int I = bi * 128;
  const int J = bj * 128;
  const bool offdiag = (bi != bj);

  const int tid  = threadIdx.x;
  const int wave = tid >> 6;
  const int lane = tid & 63;
  const bool loader = wave >= 4;       // tid >= 256
  const int gw  = wave & 3;            // role-local wave id
  const int wm  = gw >> 1;             // 0..1 row half (GEMM waves)
  const int wn  = gw & 1;              // 0..1 col half
  const int q   = lane >> 4;           // 0..3
  const int c16 = lane & 15;           // 0..15

  __shared__ alignas(16) unsigned short lA[128 * 32];
  __shared__ alignas(16) unsigned short lB[128 * 32];
  __shared__ float sacc[2][128][3];    // [panel][row][Spos,Sneg,Pcnt]
  // packed mask bits: [kind][row][word64 + pad]; kind 0=posD 1=negD 2=posT 3=negT
  __shared__ unsigned long long pk[4][128][3];
  for (int t = tid; t < 2 * 128 * 3; t += 512) ((float*)sacc)[t] = 0.f;

  f32x4 acc[4][4];
  int mv[16];   // loader waves: in-flight mask batch (lives across raw barriers)

  if (!loader) {
    const f32x4 z4 = {0.f, 0.f, 0.f, 0.f};
    #pragma unroll
    for (int mt = 0; mt < 4; ++mt)
      #pragma unroll
      for (int nt = 0; nt < 4; ++nt) acc[mt][nt] = z4;
  }

  for (int kk = 0; kk < DD / 32; ++kk) {
    if (!loader) {
      // ---- GEMM role: stage, sync, MFMA, sync (m97 pattern) ----
      const int k0 = kk * 32;
      #pragma unroll
      for (int c = 0; c < 2; ++c) {
        const int fidx = tid + c * 256;        // tid<256 here -> 0..511 chunks
        const int L    = fidx >> 2;            // LDS row 0..127
        const int p    = fidx & 3;
        const int csrc = (p ^ ((L >> 1) & 3)) & 3;     // chunk XOR swizzle
        // lA: natural row order (R8-proven, 0 conflicts)
        async16(fnb + (size_t)(I + L) * DD + k0 + csrc * 8, (char*)lA + fidx * 16);
        // lB: row-permuted so MFMA B-reads (global row 4*c16+t) stay 2-way in banks
        const int gB = 4 * (L & 31) + (L >> 5);        // inverse of L(brow)
        async16(fnb + (size_t)(J + gB) * DD + k0 + csrc * 8, (char*)lB + fidx * 16);
      }
      __syncthreads();   // mid: drains OWN staging only; barrier arrival

      s16x8 aF[4], bF[4];
      #pragma unroll
      for (int t = 0; t < 4; ++t) {
        const int arow = wm * 64 + t * 16 + c16;
        const int apos = (q ^ ((arow >> 1) & 3)) & 3;
        aF[t] = *(const s16x8*)((const char*)lA + arow * 64 + apos * 16);
        // want global row brow = wn*64 + 4*c16 + t  ->  LDS row L(brow)
        const int Lb = (wn * 16 + c16) | (t << 5);
        const int bpos = (q ^ ((Lb >> 1) & 3)) & 3;
        bF[t] = *(const s16x8*)((const char*)lB + Lb * 64 + bpos * 16);
      }
      #pragma unroll
      for (int mt = 0; mt < 4; ++mt)
        #pragma unroll
        for (int nt = 0; nt < 4; ++nt)
          acc[mt][nt] = __builtin_amdgcn_mfma_f32_16x16x32_bf16(aF[mt], bF[nt], acc[mt][nt], 0, 0, 0);
      __syncthreads();   // end: protect lA/lB for next staging
    } else {
      // ---- loader role: consume prev batch, issue next, 2 raw barriers ----
      const int lw = wave - 4;
      if (kk > 0) {
        const int pkd = (kk - 1) & 3;
        if (pkd < 2 || offdiag) {
          // batch issued a full iteration ago; compiler-tracked vmcnt wait
          consume_masks(mv, pkd, ((kk - 1) >> 2) * 32 + lw * 8, pk, lane);
        }
      }
      const int kd    = kk & 3;
      const int slice = kk >> 2;
      if (kd < 2 || offdiag) {
        const int rbase = (kd & 2) ? J : I;
        const int cbase = (kd & 2) ? I : J;
        const int* __restrict__ mp = (kd & 1) ? negm : posm;
        const int trow0 = slice * 32 + lw * 8;
        #pragma unroll
        for (int j = 0; j < 16; ++j) {
          const int trow = trow0 + (j >> 1);
          mv[j] = mp[(size_t)(rbase + trow) * NN + cbase + (j & 1) * 64 + lane];
        }
      }
      // arrive both barriers WITHOUT draining the in-flight mask loads
      __builtin_amdgcn_sched_barrier(0);
      __builtin_amdgcn_s_barrier();      // mid
      __builtin_amdgcn_sched_barrier(0);
      __builtin_amdgcn_s_barrier();      // end
      __builtin_amdgcn_sched_barrier(0);
    }
  }

  // final batch (kk=15, kind 3) was issued only by off-diagonal blocks
  if (loader && offdiag) {
    consume_masks(mv, 3, 3 * 32 + (wave - 4) * 8, pk, lane);
  }
  __syncthreads();   // all 8 waves: pk complete & visible

  // ---- epilogue: GEMM waves only; pure LDS/VALU, no global loads ----
  if (!loader) {
    // acc[mt][nt][r] = sim[I + wm*64 + mt*16 + q*4 + r][J + wn*64 + 4*c16 + nt]
    #pragma unroll
    for (int mt = 0; mt < 4; ++mt)
      #pragma unroll
      for (int nt = 0; nt < 4; ++nt)
        #pragma unroll
        for (int r = 0; r < 4; ++r)
          acc[mt][nt][r] = __expf(acc[mt][nt][r] * INV_T - INV_T);

    const bool hasdiag = (bi == bj) && (wm == wn);
    const int cb = wn * 64 + 4 * c16;            // local col base
    const int half = c16 >> 3;                   // which 32b half of the 64b word
    const int bsh  = 4 * (c16 & 7);              // bit base within the half

    // direct pass: rows I.., cols J..
    #pragma unroll
    for (int mt = 0; mt < 4; ++mt) {
      const int rl = wm * 64 + mt * 16 + q * 4;  // local row base
      #pragma unroll
      for (int r = 0; r < 4; ++r) {
        const int row = rl + r;
        const uint2 pw = *(const uint2*)&pk[0][row][wn];
        const uint2 nw = *(const uint2*)&pk[1][row][wn];
        const unsigned int p32 = half ? pw.y : pw.x;
        const unsigned int n32 = half ? nw.y : nw.x;
        float dsp = 0.f, dsn = 0.f, dpc = 0.f;
        #pragma unroll
        for (int nt = 0; nt < 4; ++nt) {
          float pf = (float)((p32 >> (bsh + nt)) & 1u);
          float nf = (float)((n32 >> (bsh + nt)) & 1u);
          if (hasdiag && (row == cb + nt)) { pf = 0.f; nf = 0.f; }  // self-contrast diag
          const float e = acc[mt][nt][r];
          dsp = fmaf(e, pf, dsp);
          dsn = fmaf(e, nf, dsn);
          dpc += pf;
        }
        #pragma unroll
        for (int o = 1; o <= 8; o <<= 1) {
          dsp += __shfl_xor(dsp, o);
          dsn += __shfl_xor(dsn, o);
          dpc += __shfl_xor(dpc, o);
        }
        if (c16 == 0) {   // LDS atomics: lgkmcnt only
          atomicAdd(&sacc[0][row][0], dsp);
          atomicAdd(&sacc[0][row][1], dsn);
          atomicAdd(&sacc[0][row][2], dpc);
        }
      }
    }

    // transposed pass: sim(col,row) == sim(row,col); rows J.., cols I..
    if (offdiag) {
      #pragma unroll
      for (int nt = 0; nt < 4; ++nt) {
        const int trl = cb + nt;                 // local row in J-panel
        const uint2 pw = *(const uint2*)&pk[2][trl][wm];
        const uint2 nw = *(const uint2*)&pk[3][trl][wm];
        float ts = 0.f, tn = 0.f, tp = 0.f;
        #pragma unroll
        for (int mt = 0; mt < 4; ++mt) {
          const unsigned int p32 = (mt < 2) ? pw.x : pw.y;
          const unsigned int n32 = (mt < 2) ? nw.x : nw.y;
          #pragma unroll
          for (int r = 0; r < 4; ++r) {
            const int bit = (mt & 1) * 16 + q * 4 + r;
            const float pf = (float)((p32 >> bit) & 1u);
            const float nf = (float)((n32 >> bit) & 1u);
            const float e = acc[mt][nt][r];
            ts = fmaf(e, pf, ts);
            tn = fmaf(e, nf, tn);
            tp += pf;
          }
        }
        ts += __shfl_xor(ts, 16); ts += __shfl_xor(ts, 32);
        tn += __shfl_xor(tn, 16); tn += __shfl_xor(tn, 32);
        tp += __shfl_xor(tp, 16); tp += __shfl_xor(tp, 32);
        if (q == 0) {
          atomicAdd(&sacc[1][trl][0], ts);
          atomicAdd(&sacc[1][trl][1], tn);
          atomicAdd(&sacc[1][trl][2], tp);
        }
      }
    }
  }

  __syncthreads();

  // one batch of global atomics at the very end; nothing waits on them
  const int r = tid & 127;
  if (tid < 128) {
    atomicAdd(&Spos[I + r], sacc[0][r][0]);
    atomicAdd(&Sneg[I + r], sacc[0][r][1]);
    atomicAdd(&Pcnt[I + r], sacc[0][r][2]);
  } else if (tid < 256 && offdiag) {
    atomicAdd(&Spos[J + r], sacc[1][r][0]);
    atomicAdd(&Sneg[J + r], sacc[1][r][1]);
    atomicAdd(&Pcnt[J + r], sacc[1][r][2]);
  }
}

// ---------------- Kernel C: finalize ----------------
__global__ __launch_bounds__(256) void finalize_kernel(const float* __restrict__ Spos,
                                                       const float* __restrict__ Sneg,
                                                       const float* __restrict__ Pcnt,
                                                       float* __restrict__ out) {
  float local = 0.f;
  for (int i = threadIdx.x; i < NN; i += 256) {
    const float sp = Spos[i], sn = Sneg[i], pc = Pcnt[i];
    const float card = (pc == 0.f) ? 1.f : pc;
    local += (logf(sn) * pc - sp) / card;
  }
  #pragma unroll
  for (int o = 32; o; o >>= 1) local += __shfl_xor(local, o);
  __shared__ float red[4];
  if ((threadIdx.x & 63) == 0) red[threadIdx.x >> 6] = local;
  __syncthreads();
  if (threadIdx.x == 0)
    out[0] = (red[0] + red[1] + red[2] + red[3]) * (1.0f / (float)NN);
}

extern "C" void kernel_launch(void* const* d_in, const int* in_sizes, int n_in,
                              void* d_out, int out_size, void* d_ws, size_t ws_size,
                              hipStream_t stream) {
  const float* feat = (const float*)d_in[0];
  const int* posm   = (const int*)d_in[1];
  const int* negm   = (const int*)d_in[2];
  float* out = (float*)d_out;

  char* ws = (char*)d_ws;
  unsigned short* fnb = (unsigned short*)ws;                 // 8 MB
  float* Spos = (float*)(ws + (size_t)8 * 1024 * 1024);
  float* Sneg = Spos + NN;
  float* Pcnt = Sneg + NN;

  normalize_kernel<<<NN / 4, 256, 0, stream>>>(feat, fnb, Spos);
  fused_kernel<<<2080, 512, 0, stream>>>(fnb, posm, negm, Spos, Sneg, Pcnt);
  finalize_kernel<<<1, 256, 0, stream>>>(Spos, Sneg, Pcnt, out);
}